// Round 3
// baseline (218.900 us; speedup 1.0000x reference)
//
#include <hip/hip_runtime.h>

// Neural stack, closed form. Round 9: R8's persistent work-stealing design
// with the launch-size bug fixed (grid must be 2048 blocks = 8192 waves to
// match the static seeding of 2 rows/wave; R8 launched 512 blocks and left
// 3/4 of the seeded row range unprocessed).
//
// s_j^(t) = relu(d_j - relu(max_{j<tau<=t} G_tau - H_j)),
//   G_tau = U_tau - Dp_{tau-1}, H_j = U_j - Dp_j  (prefix sums of u, d).
// Per row t (p = t - j): M = exclusive prefix-MAX of G, C = exclusive
// prefix-SUM of s, coeff = min(s, relu(1-C)); exactly 0 once C >= 1.
// Heavy rows (stack sum < 1) walk all chunks and gather many rows ->
// work stealing bounds the tail by one row's cost, not one wave's share.

#define TT 512
#define BB 128
#define EE 256
#define NROWS (TT * BB)             // 65536
#define NSTREAM 4
#define SPSTREAM (NROWS / NSTREAM)  // 16384 rows per stream
#define NBLOCK 2048                 // exact device capacity at 256 thr/block
#define WPSTREAM (NBLOCK * 4 / NSTREAM)  // 2048 waves per stream
#define SEED (WPSTREAM * 2)         // rows pre-assigned per stream (4096)

typedef float v4f __attribute__((ext_vector_type(4)));

// packed per-(b,t): {G, H, d, 0} — one coalesced dwordx4 per lane per chunk
__device__ v4f g_GHD[BB * TT];
__device__ unsigned g_ctr[NSTREAM * 16];   // 64B-padded work queues

template <int CTRL, int RM>
__device__ __forceinline__ float dppmov(float o, float s) {
  return __int_as_float(__builtin_amdgcn_update_dpp(
      __float_as_int(o), __float_as_int(s), CTRL, RM, 0xf, false));
}

__device__ __forceinline__ float readlanef(float v, int l) {
  return __int_as_float(__builtin_amdgcn_readlane(__float_as_int(v), l));
}

// wave64 inclusive max-scan (identity -inf)
__device__ __forceinline__ float scan_max64(float v) {
  const float NI = -__builtin_inff();
  v = fmaxf(v, dppmov<0x111, 0xf>(NI, v));   // row_shr:1
  v = fmaxf(v, dppmov<0x112, 0xf>(NI, v));   // row_shr:2
  v = fmaxf(v, dppmov<0x114, 0xf>(NI, v));   // row_shr:4
  v = fmaxf(v, dppmov<0x118, 0xf>(NI, v));   // row_shr:8
  v = fmaxf(v, dppmov<0x142, 0xa>(NI, v));   // row_bcast:15 -> rows 1,3
  v = fmaxf(v, dppmov<0x143, 0xc>(NI, v));   // row_bcast:31 -> rows 2,3
  return v;
}

// wave64 inclusive sum-scan (identity 0)
__device__ __forceinline__ float scan_add64(float v) {
  v += dppmov<0x111, 0xf>(0.f, v);
  v += dppmov<0x112, 0xf>(0.f, v);
  v += dppmov<0x114, 0xf>(0.f, v);
  v += dppmov<0x118, 0xf>(0.f, v);
  v += dppmov<0x142, 0xa>(0.f, v);
  v += dppmov<0x143, 0xc>(0.f, v);
  return v;
}

// whole-wave shift right by 1 (lane0 <- carry)
__device__ __forceinline__ float wshr1(float carry, float v) {
  return __int_as_float(__builtin_amdgcn_update_dpp(
      __float_as_int(carry), __float_as_int(v), 0x138, 0xf, 0xf, false));
}

// ---------------------------------------------------------------------------
// Kernel A: per-batch f64 prefix sums of u,d -> packed (G,H,d) table,
// plus work-queue seeding. One wave per b.
// ---------------------------------------------------------------------------
__global__ __launch_bounds__(64) void precompute_kernel(
    const float* __restrict__ u, const float* __restrict__ d) {
  const int b = blockIdx.x;
  const int lane = threadIdx.x;

  if (b == 0 && lane < NSTREAM) g_ctr[lane * 16] = SEED;

  double su[8], sv[8];
  float dv[8];
#pragma unroll
  for (int c = 0; c < 8; ++c) {
    const int t = c * 64 + lane;
    const float uv = u[t * BB + b];
    const float dd = d[t * BB + b];
    dv[c] = dd;
    su[c] = (double)uv;
    sv[c] = (double)dd;
  }
#pragma unroll
  for (int o = 1; o < 64; o <<= 1) {
#pragma unroll
    for (int c = 0; c < 8; ++c) {
      const double yu = __shfl_up(su[c], o);
      const double yv = __shfl_up(sv[c], o);
      if (lane >= o) { su[c] += yu; sv[c] += yv; }
    }
  }
  double oU = 0.0, oD = 0.0;
#pragma unroll
  for (int c = 0; c < 8; ++c) {
    const double U = oU + su[c];
    const double D = oD + sv[c];
    v4f w;
    w.x = (float)(U - (D - (double)dv[c]));  // G_t = U_t - Dp_{t-1}
    w.y = (float)(U - D);                    // H_t = U_t - Dp_t
    w.z = dv[c];
    w.w = 0.f;
    g_GHD[b * TT + c * 64 + lane] = w;
    oU += __shfl(su[c], 63);
    oD += __shfl(sv[c], 63);
  }
}

// ---------------------------------------------------------------------------
// One row's walk. p = position from the top (p=0 -> j=t).
// ---------------------------------------------------------------------------
__device__ __forceinline__ void do_row(int t, int b, const float* __restrict__ v,
                                       float* __restrict__ out, int lane) {
  const v4f* __restrict__ GHD = g_GHD + b * TT;
  const v4f* __restrict__ vb = (const v4f*)(v + b * EE);
  const float NI = -__builtin_inff();

  v4f acc = {0.f, 0.f, 0.f, 0.f};
  float Ccarry = 0.f;
  float Mcarry = NI;

  // chunk 0 table read
  int j0 = t - lane;
  v4f gh = GHD[j0 < 0 ? 0 : j0];

  for (int base = 0; base <= t; base += 64) {
    const bool in = (base + lane <= t);

    // speculative next-chunk prefetch (clamped; overlaps the gather below)
    const int jn = t - (base + 64 + lane);
    const v4f ghn = GHD[jn < 0 ? 0 : jn];

    const float Gv = in ? gh.x : NI;
    const float Hv = in ? gh.y : 0.f;
    const float dvv = in ? gh.z : 0.f;

    const float gmax = scan_max64(Gv);                     // incl max of G
    const float Mex = fmaxf(wshr1(Mcarry, gmax), Mcarry);  // excl + carry

    const float s = fmaxf(dvv - fmaxf(Mex - Hv, 0.f), 0.f);

    const float csum = scan_add64(s);                      // incl sum of s
    const float Cex = wshr1(0.f, csum) + Ccarry;           // excl + carry

    const float coeff = fminf(s, fmaxf(1.f - Cex, 0.f));

    unsigned long long m = __ballot(coeff > 0.f);
    while (m) {
      if (__popcll(m) <= 4) {
        // common case: up to 4 rows, one wait
        const int l0 = __ffsll(m) - 1; m &= m - 1;
        int k1 = l0, k2 = l0, k3 = l0;
        float f1 = 0.f, f2 = 0.f, f3 = 0.f;
        if (m) { k1 = __ffsll(m) - 1; m &= m - 1; f1 = 1.f; }
        if (m) { k2 = __ffsll(m) - 1; m &= m - 1; f2 = 1.f; }
        if (m) { k3 = __ffsll(m) - 1; m &= m - 1; f3 = 1.f; }

        const float c0 = readlanef(coeff, l0);
        const float c1 = f1 * readlanef(coeff, k1);
        const float c2 = f2 * readlanef(coeff, k2);
        const float c3 = f3 * readlanef(coeff, k3);

        const v4f y0 = vb[((t - base - l0) << 13) + lane];
        const v4f y1 = vb[((t - base - k1) << 13) + lane];
        const v4f y2 = vb[((t - base - k2) << 13) + lane];
        const v4f y3 = vb[((t - base - k3) << 13) + lane];

        acc += c0 * y0;
        acc += c1 * y1;
        acc += c2 * y2;
        acc += c3 * y3;
      } else {
        // heavy case: 8-deep pipeline
        int kk[8];
        float ff[8];
        const int l0 = __ffsll(m) - 1; m &= m - 1;
        kk[0] = l0; ff[0] = 1.f;
#pragma unroll
        for (int z = 1; z < 8; ++z) {
          if (m) { kk[z] = __ffsll(m) - 1; m &= m - 1; ff[z] = 1.f; }
          else   { kk[z] = l0; ff[z] = 0.f; }
        }
        float cc[8];
#pragma unroll
        for (int z = 0; z < 8; ++z) cc[z] = ff[z] * readlanef(coeff, kk[z]);
        v4f yy[8];
#pragma unroll
        for (int z = 0; z < 8; ++z)
          yy[z] = vb[((t - base - kk[z]) << 13) + lane];
#pragma unroll
        for (int z = 0; z < 8; ++z) acc += cc[z] * yy[z];
      }
    }

    Ccarry = Ccarry + readlanef(csum, 63);
    Mcarry = fmaxf(Mcarry, readlanef(gmax, 63));
    if (Ccarry >= 1.f) break;            // all deeper coeffs exactly 0
    gh = ghn;
  }

  v4f* op = (v4f*)(out + ((size_t)t * BB + b) * EE);
  __builtin_nontemporal_store(acc, op + lane);
}

// ---------------------------------------------------------------------------
// Kernel B: persistent work-stealing waves. Row id rid (deepest-first):
//   t = 511 - (rid >> 7), b = rid & 127.
// Stream c = wave index handles rids {4m + c}; each wave statically takes
// batch (wid>>2)*2 .. +1, then grabs 2-row batches from g_ctr[c].
// Grid = NBLOCK = exact device capacity (8 blocks/CU, 32 waves/CU).
// ---------------------------------------------------------------------------
__launch_bounds__(256)
__global__ void stack_kernel(const float* __restrict__ v,
                             float* __restrict__ out) {
  const int wave = threadIdx.x >> 6;
  const int lane = threadIdx.x & 63;
  const int wid = (blockIdx.x << 2) | wave;
  const int strm = wid & 3;

  unsigned n = (unsigned)(wid >> 2) * 2u;   // static first batch

  while (true) {
#pragma unroll 1
    for (int e = 0; e < 2; ++e) {
      const unsigned mrow = n + e;
      if (mrow >= SPSTREAM) break;
      const int rid = (int)(mrow << 2) + strm;
      const int t = (TT - 1) - (rid >> 7);
      const int b = rid & (BB - 1);
      do_row(t, b, v, out, lane);
    }
    unsigned nx = 0;
    if (lane == 0) nx = atomicAdd(&g_ctr[strm * 16], 2u);
    n = (unsigned)__builtin_amdgcn_readfirstlane((int)nx);
    if (n >= SPSTREAM) break;
  }
}

extern "C" void kernel_launch(void* const* d_in, const int* in_sizes, int n_in,
                              void* d_out, int out_size, void* d_ws,
                              size_t ws_size, hipStream_t stream) {
  const float* v = (const float*)d_in[0];
  const float* u = (const float*)d_in[1];
  const float* dd = (const float*)d_in[2];
  float* out = (float*)d_out;
  (void)in_sizes; (void)n_in; (void)out_size; (void)d_ws; (void)ws_size;

  hipLaunchKernelGGL(precompute_kernel, dim3(BB), dim3(64), 0, stream, u, dd);
  hipLaunchKernelGGL(stack_kernel, dim3(NBLOCK), dim3(256), 0, stream,
                     v, out);
}

// Round 4
// 129.281 us; speedup vs baseline: 1.6932x; 1.6932x over previous
//
#include <hip/hip_runtime.h>

// Neural stack, closed form. Round 10: per-BATCH work stealing.
// R9's global deepest-first queue balanced load but scrambled b across the
// waves of each block -> every gather/table read lost L1/L2 locality
// (FETCH doubled, VALUBusy 33->13.6%, 3x slower). R10 keeps R7's layout
// (block = (g,b), all 4 waves share batch b; 16 blocks = 64 waves per b)
// and makes the ROW assignment within each batch dynamic: per-b atomic
// counter hands out rows deepest-first (LPT). Balance of R9, locality of R7.
//
// s_j^(t) = relu(d_j - relu(max_{j<tau<=t} G_tau - H_j)),
//   G_tau = U_tau - Dp_{tau-1}, H_j = U_j - Dp_j  (prefix sums of u, d).
// Per row t (p = t - j): M = exclusive prefix-MAX of G, C = exclusive
// prefix-SUM of s, coeff = min(s, relu(1-C)); exactly 0 once C >= 1.

#define TT 512
#define BB 128
#define EE 256
#define NBLOCK 2048                 // (16 g) x (128 b); 8 blocks/CU
#define WPB 64                      // waves per batch: 16 blocks x 4 waves
#define SEEDN WPB                   // rows 0..63 statically assigned

typedef float v4f __attribute__((ext_vector_type(4)));

// packed per-(b,t): {G, H, d, 0} — one coalesced dwordx4 per lane per chunk
__device__ v4f g_GHD[BB * TT];
__device__ unsigned g_ctr[BB * 16];   // per-batch row queue, 64B padded

template <int CTRL, int RM>
__device__ __forceinline__ float dppmov(float o, float s) {
  return __int_as_float(__builtin_amdgcn_update_dpp(
      __float_as_int(o), __float_as_int(s), CTRL, RM, 0xf, false));
}

__device__ __forceinline__ float readlanef(float v, int l) {
  return __int_as_float(__builtin_amdgcn_readlane(__float_as_int(v), l));
}

// wave64 inclusive max-scan (identity -inf)
__device__ __forceinline__ float scan_max64(float v) {
  const float NI = -__builtin_inff();
  v = fmaxf(v, dppmov<0x111, 0xf>(NI, v));   // row_shr:1
  v = fmaxf(v, dppmov<0x112, 0xf>(NI, v));   // row_shr:2
  v = fmaxf(v, dppmov<0x114, 0xf>(NI, v));   // row_shr:4
  v = fmaxf(v, dppmov<0x118, 0xf>(NI, v));   // row_shr:8
  v = fmaxf(v, dppmov<0x142, 0xa>(NI, v));   // row_bcast:15 -> rows 1,3
  v = fmaxf(v, dppmov<0x143, 0xc>(NI, v));   // row_bcast:31 -> rows 2,3
  return v;
}

// wave64 inclusive sum-scan (identity 0)
__device__ __forceinline__ float scan_add64(float v) {
  v += dppmov<0x111, 0xf>(0.f, v);
  v += dppmov<0x112, 0xf>(0.f, v);
  v += dppmov<0x114, 0xf>(0.f, v);
  v += dppmov<0x118, 0xf>(0.f, v);
  v += dppmov<0x142, 0xa>(0.f, v);
  v += dppmov<0x143, 0xc>(0.f, v);
  return v;
}

// whole-wave shift right by 1 (lane0 <- carry)
__device__ __forceinline__ float wshr1(float carry, float v) {
  return __int_as_float(__builtin_amdgcn_update_dpp(
      __float_as_int(carry), __float_as_int(v), 0x138, 0xf, 0xf, false));
}

// ---------------------------------------------------------------------------
// Kernel A: per-batch f64 prefix sums of u,d -> packed (G,H,d) table,
// plus per-batch queue seeding. One wave per b.
// ---------------------------------------------------------------------------
__global__ __launch_bounds__(64) void precompute_kernel(
    const float* __restrict__ u, const float* __restrict__ d) {
  const int b = blockIdx.x;
  const int lane = threadIdx.x;

  if (lane == 0) g_ctr[b * 16] = SEEDN;

  double su[8], sv[8];
  float dv[8];
#pragma unroll
  for (int c = 0; c < 8; ++c) {
    const int t = c * 64 + lane;
    const float uv = u[t * BB + b];
    const float dd = d[t * BB + b];
    dv[c] = dd;
    su[c] = (double)uv;
    sv[c] = (double)dd;
  }
#pragma unroll
  for (int o = 1; o < 64; o <<= 1) {
#pragma unroll
    for (int c = 0; c < 8; ++c) {
      const double yu = __shfl_up(su[c], o);
      const double yv = __shfl_up(sv[c], o);
      if (lane >= o) { su[c] += yu; sv[c] += yv; }
    }
  }
  double oU = 0.0, oD = 0.0;
#pragma unroll
  for (int c = 0; c < 8; ++c) {
    const double U = oU + su[c];
    const double D = oD + sv[c];
    v4f w;
    w.x = (float)(U - (D - (double)dv[c]));  // G_t = U_t - Dp_{t-1}
    w.y = (float)(U - D);                    // H_t = U_t - Dp_t
    w.z = dv[c];
    w.w = 0.f;
    g_GHD[b * TT + c * 64 + lane] = w;
    oU += __shfl(su[c], 63);
    oD += __shfl(sv[c], 63);
  }
}

// ---------------------------------------------------------------------------
// One row's walk. p = position from the top (p=0 -> j=t).
// ---------------------------------------------------------------------------
__device__ __forceinline__ void do_row(int t, int b, const float* __restrict__ v,
                                       float* __restrict__ out, int lane) {
  const v4f* __restrict__ GHD = g_GHD + b * TT;
  const v4f* __restrict__ vb = (const v4f*)(v + b * EE);
  const float NI = -__builtin_inff();

  v4f acc = {0.f, 0.f, 0.f, 0.f};
  float Ccarry = 0.f;
  float Mcarry = NI;

  // chunk 0 table read
  int j0 = t - lane;
  v4f gh = GHD[j0 < 0 ? 0 : j0];

  for (int base = 0; base <= t; base += 64) {
    const bool in = (base + lane <= t);

    // speculative next-chunk prefetch (clamped; overlaps the gather below)
    const int jn = t - (base + 64 + lane);
    const v4f ghn = GHD[jn < 0 ? 0 : jn];

    const float Gv = in ? gh.x : NI;
    const float Hv = in ? gh.y : 0.f;
    const float dvv = in ? gh.z : 0.f;

    const float gmax = scan_max64(Gv);                     // incl max of G
    const float Mex = fmaxf(wshr1(Mcarry, gmax), Mcarry);  // excl + carry

    const float s = fmaxf(dvv - fmaxf(Mex - Hv, 0.f), 0.f);

    const float csum = scan_add64(s);                      // incl sum of s
    const float Cex = wshr1(0.f, csum) + Ccarry;           // excl + carry

    const float coeff = fminf(s, fmaxf(1.f - Cex, 0.f));

    unsigned long long m = __ballot(coeff > 0.f);
    while (m) {
      if (__popcll(m) <= 4) {
        // common case: up to 4 rows, one wait
        const int l0 = __ffsll(m) - 1; m &= m - 1;
        int k1 = l0, k2 = l0, k3 = l0;
        float f1 = 0.f, f2 = 0.f, f3 = 0.f;
        if (m) { k1 = __ffsll(m) - 1; m &= m - 1; f1 = 1.f; }
        if (m) { k2 = __ffsll(m) - 1; m &= m - 1; f2 = 1.f; }
        if (m) { k3 = __ffsll(m) - 1; m &= m - 1; f3 = 1.f; }

        const float c0 = readlanef(coeff, l0);
        const float c1 = f1 * readlanef(coeff, k1);
        const float c2 = f2 * readlanef(coeff, k2);
        const float c3 = f3 * readlanef(coeff, k3);

        const v4f y0 = vb[((t - base - l0) << 13) + lane];
        const v4f y1 = vb[((t - base - k1) << 13) + lane];
        const v4f y2 = vb[((t - base - k2) << 13) + lane];
        const v4f y3 = vb[((t - base - k3) << 13) + lane];

        acc += c0 * y0;
        acc += c1 * y1;
        acc += c2 * y2;
        acc += c3 * y3;
      } else {
        // heavy case: 8-deep pipeline
        int kk[8];
        float ff[8];
        const int l0 = __ffsll(m) - 1; m &= m - 1;
        kk[0] = l0; ff[0] = 1.f;
#pragma unroll
        for (int z = 1; z < 8; ++z) {
          if (m) { kk[z] = __ffsll(m) - 1; m &= m - 1; ff[z] = 1.f; }
          else   { kk[z] = l0; ff[z] = 0.f; }
        }
        float cc[8];
#pragma unroll
        for (int z = 0; z < 8; ++z) cc[z] = ff[z] * readlanef(coeff, kk[z]);
        v4f yy[8];
#pragma unroll
        for (int z = 0; z < 8; ++z)
          yy[z] = vb[((t - base - kk[z]) << 13) + lane];
#pragma unroll
        for (int z = 0; z < 8; ++z) acc += cc[z] * yy[z];
      }
    }

    Ccarry = Ccarry + readlanef(csum, 63);
    Mcarry = fmaxf(Mcarry, readlanef(gmax, 63));
    if (Ccarry >= 1.f) break;            // all deeper coeffs exactly 0
    gh = ghn;
  }

  v4f* op = (v4f*)(out + ((size_t)t * BB + b) * EE);
  __builtin_nontemporal_store(acc, op + lane);
}

// ---------------------------------------------------------------------------
// Kernel B: per-batch work stealing. Block (g,b): b = bid & 127, g = bid>>7.
// Wave-of-batch wb = g*4 + wave (0..63) statically takes row n=wb, then
// steals single rows from g_ctr[b] (deepest-first: t = 511 - n).
// All 4 waves of a block share batch b -> GHD + v-slice stay L1/L2 hot.
// ---------------------------------------------------------------------------
__launch_bounds__(256)
__global__ void stack_kernel(const float* __restrict__ v,
                             float* __restrict__ out) {
  const int b = blockIdx.x & (BB - 1);
  const int g = blockIdx.x >> 7;          // 0..15
  const int wave = threadIdx.x >> 6;
  const int lane = threadIdx.x & 63;
  const int wb = (g << 2) | wave;         // 0..63, wave index within batch

  unsigned n = (unsigned)wb;              // static first row (deepest 64)

  while (n < TT) {
    const int t = (TT - 1) - (int)n;
    do_row(t, b, v, out, lane);
    unsigned nx = 0;
    if (lane == 0) nx = atomicAdd(&g_ctr[b * 16], 1u);
    n = (unsigned)__builtin_amdgcn_readfirstlane((int)nx);
  }
}

extern "C" void kernel_launch(void* const* d_in, const int* in_sizes, int n_in,
                              void* d_out, int out_size, void* d_ws,
                              size_t ws_size, hipStream_t stream) {
  const float* v = (const float*)d_in[0];
  const float* u = (const float*)d_in[1];
  const float* dd = (const float*)d_in[2];
  float* out = (float*)d_out;
  (void)in_sizes; (void)n_in; (void)out_size; (void)d_ws; (void)ws_size;

  hipLaunchKernelGGL(precompute_kernel, dim3(BB), dim3(64), 0, stream, u, dd);
  hipLaunchKernelGGL(stack_kernel, dim3(NBLOCK), dim3(256), 0, stream,
                     v, out);
}